// Round 3
// baseline (102.855 us; speedup 1.0000x reference)
//
#include <hip/hip_runtime.h>

#define FEAT 512
#define REL_DIM 64
#define N_DRUGS 2000
#define N_TARGETS 4000
#define N_ENT_ROWS (N_DRUGS + N_TARGETS)
#define N_TRI 131072

__device__ __forceinline__ float dot4(float4 a, float4 b) {
    return a.x * b.x + a.y * b.y + a.z * b.z + a.w * b.w;
}

__device__ __forceinline__ float waveReduce(float v) {
#pragma unroll
    for (int off = 32; off; off >>= 1) v += __shfl_xor(v, off, 64);
    return v;
}

// tanh via exp2-based exp: tanh(x) = 1 - 2/(e^{2x}+1).
// v_rcp_f32 rel err ~1e-7; saturates correctly for |x| large (inf -> 1, 0 -> -1).
__device__ __forceinline__ float fast_tanh(float x) {
    const float e = __expf(2.0f * x);
    return 1.0f - 2.0f * __builtin_amdgcn_rcpf(e + 1.0f);
}

// One wave per entity row. Rows [0,2000)=drugs, [2000,6000)=targets,
// row 6000 = the 8 relation scalars (both branches).
// Packed outputs: preU[row]=(fu.Wu_intra, fu.Wu_inter), preV[row]=(fv.Wv_intra, fv.Wv_inter),
// relC[r]=(re.Wr_intra+b_intra, re.Wr_inter+b_inter).
__global__ __launch_bounds__(256) void precompute_kernel(
    const float* __restrict__ d_intra, const float* __restrict__ d_inter,
    const float* __restrict__ t_intra, const float* __restrict__ t_inter,
    const float* __restrict__ rel_emb_intra, const float* __restrict__ rel_emb_inter,
    const float* __restrict__ W_intra, const float* __restrict__ b_intra,
    const float* __restrict__ W_inter, const float* __restrict__ b_inter,
    float2* __restrict__ preU, float2* __restrict__ preV,
    float2* __restrict__ relC)
{
    const int wave = threadIdx.x >> 6;
    const int lane = threadIdx.x & 63;
    const int row  = blockIdx.x * 4 + wave;

    if (row < N_ENT_ROWS) {
        const float* fA;  // intra features
        const float* fB;  // inter features
        if (row < N_DRUGS) {
            fA = d_intra + (size_t)row * FEAT;
            fB = d_inter + (size_t)row * FEAT;
        } else {
            const int t = row - N_DRUGS;
            fA = t_intra + (size_t)t * FEAT;
            fB = t_inter + (size_t)t * FEAT;
        }
        // 512 floats = 128 float4; lane i handles float4 #i and #(i+64).
        const float4* a4 = (const float4*)fA;
        const float4* b4 = (const float4*)fB;
        const float4* w1 = (const float4*)W_intra;  // float4s: [0,128)=Wu [128,256)=Wv
        const float4* w2 = (const float4*)W_inter;

        const float4 aA0 = a4[lane],        aA1 = a4[lane + 64];
        const float4 bB0 = b4[lane],        bB1 = b4[lane + 64];
        const float4 wu10 = w1[lane],       wu11 = w1[lane + 64];
        const float4 wv10 = w1[lane + 128], wv11 = w1[lane + 192];
        const float4 wu20 = w2[lane],       wu21 = w2[lane + 64];
        const float4 wv20 = w2[lane + 128], wv21 = w2[lane + 192];

        float s_u1 = dot4(aA0, wu10) + dot4(aA1, wu11);
        float s_v1 = dot4(aA0, wv10) + dot4(aA1, wv11);
        float s_u2 = dot4(bB0, wu20) + dot4(bB1, wu21);
        float s_v2 = dot4(bB0, wv20) + dot4(bB1, wv21);

        s_u1 = waveReduce(s_u1);
        s_v1 = waveReduce(s_v1);
        s_u2 = waveReduce(s_u2);
        s_v2 = waveReduce(s_v2);

        if (lane == 0) {
            preU[row] = make_float2(s_u1, s_u2);
            preV[row] = make_float2(s_v1, s_v2);
        }
    } else if (row == N_ENT_ROWS) {
        // Relation scalars: REL_DIM==64 == wave width, one reduce per rel.
        const float b1 = b_intra[0];
        const float b2 = b_inter[0];
        const float wr1 = W_intra[2 * FEAT + lane];
        const float wr2 = W_inter[2 * FEAT + lane];
#pragma unroll
        for (int r = 0; r < 8; ++r) {
            float p1 = rel_emb_intra[r * REL_DIM + lane] * wr1;
            float p2 = rel_emb_inter[r * REL_DIM + lane] * wr2;
            p1 = waveReduce(p1);
            p2 = waveReduce(p2);
            if (lane == 0) relC[r] = make_float2(p1 + b1, p2 + b2);
        }
    }
}

// 2 triplets per thread: 65536 threads = 256 blocks x 256.
// int2 triplet loads (aligned: base int index 6i is even), branchless index
// select, float2-packed table gathers (L2-resident), float2 store.
__global__ __launch_bounds__(256) void triplet_kernel(
    const int2* __restrict__ tri2,
    const int* __restrict__ did_sub, const int* __restrict__ tid_sub,
    const float2* __restrict__ preU, const float2* __restrict__ preV,
    const float2* __restrict__ relC,
    float2* __restrict__ out2)
{
    const int i = blockIdx.x * blockDim.x + threadIdx.x;  // [0, N_TRI/2)
    const int2 p0 = tri2[3 * i + 0];
    const int2 p1 = tri2[3 * i + 1];
    const int2 p2 = tri2[3 * i + 2];

    const int us[2] = {p0.x, p1.y};
    const int vs[2] = {p0.y, p2.x};
    const int rs[2] = {p1.x, p2.y};
    float res[2];

#pragma unroll
    for (int k = 0; k < 2; ++k) {
        const int u = us[k], v = vs[k], r = rs[k];
        // u_is_drug = (r%2==0); v_is_drug = ((r/2)%2==0), r in [0,8).
        const bool ud = (r & 1) == 0;
        const bool vd = ((r >> 1) & 1) == 0;
        const int du = did_sub[u], tu = tid_sub[u];
        const int dv = did_sub[v], tv = tid_sub[v];
        const int iu = ud ? du : tu + N_DRUGS;
        const int iv = vd ? dv : tv + N_DRUGS;
        const float2 cu = preU[iu];
        const float2 cv = preV[iv];
        const float2 cr = relC[r];
        const float s1 = cu.x + cv.x + cr.x;
        const float s2 = cu.y + cv.y + cr.y;
        res[k] = 0.6f * fast_tanh(s1) + 0.2f * fast_tanh(s2);
    }
    out2[i] = make_float2(res[0], res[1]);
}

extern "C" void kernel_launch(void* const* d_in, const int* in_sizes, int n_in,
                              void* d_out, int out_size, void* d_ws, size_t ws_size,
                              hipStream_t stream) {
    const float* d_intra        = (const float*)d_in[0];
    const float* d_inter        = (const float*)d_in[1];
    const float* t_intra        = (const float*)d_in[2];
    const float* t_inter        = (const float*)d_in[3];
    const int*   did_sub        = (const int*)d_in[4];
    const int*   tid_sub        = (const int*)d_in[5];
    const int*   triplets       = (const int*)d_in[6];
    // d_in[7], d_in[8]: u_is_drug / v_is_drug — derived arithmetically from r.
    const float* rel_emb_intra  = (const float*)d_in[9];
    const float* rel_emb_inter  = (const float*)d_in[10];
    const float* W_intra        = (const float*)d_in[11];
    const float* b_intra        = (const float*)d_in[12];
    const float* W_inter        = (const float*)d_in[13];
    const float* b_inter        = (const float*)d_in[14];

    float2* ws   = (float2*)d_ws;
    float2* preU = ws;                    // 6000 float2 (drugs 0..1999, targets 2000..5999)
    float2* preV = ws + N_ENT_ROWS;       // 6000 float2
    float2* relC = preV + N_ENT_ROWS;     // 8 float2

    const int rows  = N_ENT_ROWS + 1;     // +1 wave-row for relation scalars
    const int gridA = (rows + 3) / 4;     // 4 waves/block
    precompute_kernel<<<gridA, 256, 0, stream>>>(
        d_intra, d_inter, t_intra, t_inter,
        rel_emb_intra, rel_emb_inter,
        W_intra, b_intra, W_inter, b_inter,
        preU, preV, relC);

    const int gridB = (N_TRI / 2 + 255) / 256;  // 256 blocks
    triplet_kernel<<<gridB, 256, 0, stream>>>(
        (const int2*)triplets, did_sub, tid_sub, preU, preV, relC, (float2*)d_out);
}